// Round 4
// baseline (172.773 us; speedup 1.0000x reference)
//
#include <hip/hip_runtime.h>

typedef unsigned short u16;
typedef unsigned char u8;
typedef __attribute__((ext_vector_type(8))) short short8;
typedef __attribute__((ext_vector_type(4))) short short4v;
typedef __attribute__((ext_vector_type(4))) float f32x4;

#define GLD16(g, l) __builtin_amdgcn_global_load_lds( \
    (const __attribute__((address_space(1))) void*)(g), \
    (__attribute__((address_space(3))) void*)(l), 16, 0, 0)

__device__ __forceinline__ float bf2f(u16 u){
  union { unsigned int i; float f; } v; v.i = ((unsigned int)u) << 16; return v.f;
}
__device__ __forceinline__ u16 f2bf(float f){
  union { float f; unsigned int i; } v; v.f = f;
  unsigned int u = v.i;
  unsigned int r = (u + 0x7FFFu + ((u >> 16) & 1u)) >> 16;
  return (u16)r;
}

__device__ __forceinline__ f32x4 mfma16(short4v a, short4v b, f32x4 c){
#if __has_builtin(__builtin_amdgcn_mfma_f32_16x16x16bf16_1k)
  return __builtin_amdgcn_mfma_f32_16x16x16bf16_1k(a, b, c, 0, 0, 0);
#else
  asm volatile("s_nop 1\n\tv_mfma_f32_16x16x16_bf16 %0, %1, %2, %0" : "+v"(c) : "v"(a), "v"(b));
  return c;
#endif
}

// ---------------- elementwise fp32 -> bf16 (x) ----------------
__global__ void cvt_k(const float* __restrict__ x, u16* __restrict__ o, int n4){
  int i = blockIdx.x * 256 + threadIdx.x;
  if (i >= n4) return;
  float4 v = ((const float4*)x)[i];
  unsigned long long pk = (unsigned long long)f2bf(v.x)
    | ((unsigned long long)f2bf(v.y) << 16)
    | ((unsigned long long)f2bf(v.z) << 32)
    | ((unsigned long long)f2bf(v.w) << 48);
  ((unsigned long long*)o)[i] = pk;
}

// ---------------- rel int32 -> u8 ----------------
__global__ void rel8_k(const int* __restrict__ r, u8* __restrict__ o, int n4){
  int i = blockIdx.x * 256 + threadIdx.x;
  if (i >= n4) return;
  int4 v = ((const int4*)r)[i];
  unsigned int pk = (unsigned int)(v.x & 255) | ((unsigned int)(v.y & 255) << 8)
    | ((unsigned int)(v.z & 255) << 16) | ((unsigned int)(v.w & 255) << 24);
  ((unsigned int*)o)[i] = pk;
}

// ---------------- transpose + convert weights: W[K,N] f32 -> Wt[N,K] bf16 ----------------
__global__ void tconv_k(const float* __restrict__ W, u16* __restrict__ Wt, int K, int N){
  __shared__ float tl[32][33];
  int n0 = blockIdx.x * 32, k0 = blockIdx.y * 32;
  for (int i = threadIdx.y; i < 32; i += 8)
    tl[i][threadIdx.x] = W[(size_t)(k0 + i) * N + n0 + threadIdx.x];
  __syncthreads();
  for (int i = threadIdx.y; i < 32; i += 8)
    Wt[(size_t)(n0 + i) * K + k0 + threadIdx.x] = f2bf(tl[threadIdx.x][i]);
}

// ---------------- bf16 GEMM (B^T input): C[m,n] = sum_k A[m,k]*Bt[n,k] + bias[n] ----------------
template<int MODE>
__global__ __launch_bounds__(256) void gemm_bt_k(const u16* __restrict__ A, const u16* __restrict__ Bt,
                                                 const float* __restrict__ bias,
                                                 u16* __restrict__ oq, u16* __restrict__ okk, u16* __restrict__ ov,
                                                 float* __restrict__ of,
                                                 int M, int N, int K){
  __shared__ u16 la[128 * 32];
  __shared__ u16 lb[128 * 32];
  const int t = threadIdx.x, w = t >> 6, lane = t & 63;
  const int l15 = lane & 15, l4 = lane >> 4;
  const int m0 = blockIdx.y * 128, n0 = blockIdx.x * 128;
  const int wr = w >> 1, wc = w & 1;
  f32x4 acc[4][4] = {};
  const u16* Abase = A + (size_t)m0 * K;
  const u16* Bbase = Bt + (size_t)n0 * K;
  for (int kt = 0; kt < K; kt += 32){
    __syncthreads();
#pragma unroll
    for (int i = 0; i < 2; ++i){
      int chunk = i * 256 + t;
      int row = chunk >> 2, cg = chunk & 3;
      GLD16(Abase + (size_t)row * K + kt + cg * 8, &la[(i * 256 + w * 64) * 8]);
    }
#pragma unroll
    for (int i = 0; i < 2; ++i){
      int chunk = i * 256 + t;
      int row = chunk >> 2, cg = chunk & 3;
      GLD16(Bbase + (size_t)row * K + kt + cg * 8, &lb[(i * 256 + w * 64) * 8]);
    }
    asm volatile("s_waitcnt vmcnt(0)" ::: "memory");
    __syncthreads();
    short8 af[4], bfr[4];
#pragma unroll
    for (int mi = 0; mi < 4; ++mi)
      af[mi] = *(const short8*)&la[(wr * 64 + mi * 16 + l15) * 32 + l4 * 8];
#pragma unroll
    for (int ni = 0; ni < 4; ++ni)
      bfr[ni] = *(const short8*)&lb[(wc * 64 + ni * 16 + l15) * 32 + l4 * 8];
#pragma unroll
    for (int mi = 0; mi < 4; ++mi)
#pragma unroll
      for (int ni = 0; ni < 4; ++ni)
        acc[mi][ni] = __builtin_amdgcn_mfma_f32_16x16x32_bf16(af[mi], bfr[ni], acc[mi][ni], 0, 0, 0);
  }
#pragma unroll
  for (int mi = 0; mi < 4; ++mi){
#pragma unroll
    for (int ni = 0; ni < 4; ++ni){
#pragma unroll
      for (int r = 0; r < 4; ++r){
        int m = m0 + wr * 64 + mi * 16 + l4 * 4 + r;
        int n = n0 + wc * 64 + ni * 16 + l15;
        float v = acc[mi][ni][r] + bias[n];
        if (MODE == 0){
          int tt = n >> 10, rr = n & 1023, head = rr >> 6, d = rr & 63;
          int b = m >> 11, s = m & 2047;
          u16* dst = (tt == 0) ? oq : (tt == 1) ? okk : ov;
          dst[(((size_t)(b * 16 + head)) * 2048 + s) * 64 + d] = f2bf(v);
        } else {
          of[(size_t)m * N + n] = v;
        }
      }
    }
  }
}

// ---------------- V transpose (k-field-permuted) + per-chunk column sums ----------------
// vt[bh][d][c*64 + perm(kk)] = v[bh][c*64+kk][d], perm: kk=16t+4g+r -> 16g+4t+r
__global__ __launch_bounds__(256) void transpose_v_k(const u16* __restrict__ vb, u16* __restrict__ vt,
                                                     float* __restrict__ vpart){
  __shared__ u16 tl[64][65];
  int bh = blockIdx.x >> 5, c = blockIdx.x & 31, s0 = c * 64;
  int t = threadIdx.x;
#pragma unroll
  for (int rsub = 0; rsub < 16; ++rsub){
    int idx = rsub * 256 + t;
    int i = idx >> 6, d = idx & 63;
    tl[i][d] = vb[(((size_t)bh * 2048) + s0 + i) * 64 + d];
  }
  __syncthreads();
#pragma unroll
  for (int rsub = 0; rsub < 16; ++rsub){
    int idx = rsub * 256 + t;
    int d = idx >> 6, j = idx & 63;
    int pj = (j & 3) | (((j >> 2) & 3) << 4) | (((j >> 4) & 3) << 2);
    vt[(((size_t)bh * 64) + d) * 2048 + s0 + pj] = tl[j][d];
  }
  if (t < 64){
    float s = 0.f;
#pragma unroll 8
    for (int j = 0; j < 64; ++j) s += bf2f(tl[j][t]);
    vpart[((size_t)bh * 32 + c) * 64 + t] = s;
  }
}

// ---------------- suffix scan over V chunk sums ----------------
__global__ void vsufscan_k(const float* __restrict__ vpart, float* __restrict__ vsuf){
  int bh = blockIdx.x, d = threadIdx.x;   // 64 threads
  float run = 0.f;
  vsuf[((size_t)bh * 33 + 32) * 64 + d] = 0.f;
  for (int c = 31; c >= 0; --c){
    run += vpart[((size_t)bh * 32 + c) * 64 + d];
    vsuf[((size_t)bh * 33 + c) * 64 + d] = run;
  }
}

// ---------------- fused rel-bias causal attention (swapped-operand, P-in-register) ----------------
// Paired q-tiles (qp, 31-qp): uniform 33 k-tile iterations per block.
// S^T = mfma(Kfrag, Qfrag): lane holds P[q=l15][k=16t+4*l4+r] -> exact B-frag of
// mfma_f32_16x16x16_bf16. PV^T = mfma16(Vperm-frag, Pfrag). No P LDS round-trip.
template<int U8>
__global__ __launch_bounds__(256, 2) void attn_k(const u16* __restrict__ qb, const u16* __restrict__ kb,
                                                 const u16* __restrict__ vt, const float* __restrict__ vsuf,
                                                 const void* __restrict__ relp, const float* __restrict__ rel_emb,
                                                 u16* __restrict__ ab){
  __shared__ u16 Kt[2][64 * 64];
  __shared__ u16 Vt[2][64 * 64];
  __shared__ float remb[64];
  const int qp = blockIdx.x, bh = blockIdx.y;
  const int b = bh >> 4, h = bh & 15;
  const int TA = qp, TB = 31 - qp;
  const int q0A = TA * 64, q0B = TB * 64;
  const int tid = threadIdx.x, w = tid >> 6, lane = tid & 63;
  const int l15 = lane & 15, l4 = lane >> 4;
  if (tid < 64) remb[tid] = rel_emb[tid * 16 + h] * (0.125f * 1.44269504088896f);
  const u16* kbh = kb + ((size_t)bh * 2048) * 64;
  const u16* vbh = vt + ((size_t)bh * 64) * 2048;
  const u16* qA = qb + (((size_t)bh * 2048) + q0A + w * 16 + l15) * 64 + l4 * 8;
  const u16* qB = qb + (((size_t)bh * 2048) + q0B + w * 16 + l15) * 64 + l4 * 8;
  const short8 aqA0 = *(const short8*)qA, aqA1 = *(const short8*)(qA + 32);
  const short8 aqB0 = *(const short8*)qB, aqB1 = *(const short8*)(qB + 32);
  const u8*  r8A  = (const u8*)relp + ((size_t)b * 2048 + q0A + w * 16 + l15) * 2048;
  const u8*  r8B  = (const u8*)relp + ((size_t)b * 2048 + q0B + w * 16 + l15) * 2048;
  const int* r32A = (const int*)relp + ((size_t)b * 2048 + q0A + w * 16 + l15) * 2048;
  const int* r32B = (const int*)relp + ((size_t)b * 2048 + q0B + w * 16 + l15) * 2048;

  const int srow0 = (tid >> 3), srow1 = 32 + (tid >> 3);
  const int scs = tid & 7;
  const int sc0 = scs ^ (srow0 & 7), sc1 = scs ^ (srow1 & 7);
  const int sldsoff = (w * 64) * 8;

#define STAGE(ktile, buf) do {                                                       \
    GLD16(kbh + (size_t)((ktile) * 64 + srow0) * 64 + sc0 * 8, &Kt[buf][sldsoff]);   \
    GLD16(kbh + (size_t)((ktile) * 64 + srow1) * 64 + sc1 * 8, &Kt[buf][2048 + sldsoff]); \
    GLD16(vbh + (size_t)srow0 * 2048 + (ktile) * 64 + sc0 * 8, &Vt[buf][sldsoff]);   \
    GLD16(vbh + (size_t)srow1 * 2048 + (ktile) * 64 + sc1 * 8, &Vt[buf][2048 + sldsoff]); \
  } while (0)

  f32x4 acc[4] = {};
  float rsum = 0.f;
  unsigned int relc[4], reln[4];

  auto relload = [&](bool isA, int kt, unsigned int* dst){
    int off = kt * 64 + 4 * l4;
    if (U8){
      const u8* p = isA ? r8A : r8B;
#pragma unroll
      for (int t = 0; t < 4; ++t) dst[t] = *(const unsigned int*)(p + off + 16 * t);
    } else {
      const int* p = isA ? r32A : r32B;
#pragma unroll
      for (int t = 0; t < 4; ++t){
        int4 v4 = *(const int4*)(p + off + 16 * t);
        dst[t] = (unsigned int)(v4.x & 255) | ((unsigned int)(v4.y & 255) << 8)
               | ((unsigned int)(v4.z & 255) << 16) | ((unsigned int)(v4.w & 255) << 24);
      }
    }
  };

  auto writeout = [&](int Td, int q0){
    asm volatile("s_nop 7\n\ts_nop 7" :::);
    float s = rsum;
    s += __shfl_xor(s, 16);
    s += __shfl_xor(s, 32);
    float invZ = 1.f / (s + (float)(2048 - (Td + 1) * 64));
    int qg = q0 + w * 16 + l15;
    const float* sufp = vsuf + ((size_t)bh * 33 + Td + 1) * 64;
#pragma unroll
    for (int ni = 0; ni < 4; ++ni){
      float4 sv = *(const float4*)(sufp + ni * 16 + 4 * l4);
      unsigned int lo = (unsigned int)f2bf((acc[ni][0] + sv.x) * invZ)
                      | ((unsigned int)f2bf((acc[ni][1] + sv.y) * invZ) << 16);
      unsigned int hi = (unsigned int)f2bf((acc[ni][2] + sv.z) * invZ)
                      | ((unsigned int)f2bf((acc[ni][3] + sv.w) * invZ) << 16);
      uint2 o; o.x = lo; o.y = hi;
      *(uint2*)(ab + ((size_t)b * 2048 + qg) * 1024 + h * 64 + ni * 16 + 4 * l4) = o;
    }
  };

  STAGE(0, 0);
  relload(true, 0, relc);
  __syncthreads();

  const int TOT = TA + TB + 2;   // 33
  for (int it = 0; it < TOT; ++it){
    const bool isA = (it <= TA);
    const int kt = isA ? it : (it - TA - 1);
    const int cur = it & 1;
    const int Tlim = isA ? TA : TB;

    if (it + 1 < TOT){
      const bool nIsA = (it + 1 <= TA);
      const int nkt = nIsA ? (it + 1) : (it - TA);
      STAGE(nkt, cur ^ 1);
      relload(nIsA, nkt, reln);
    }

    const short8 a0 = isA ? aqA0 : aqB0;
    const short8 a1 = isA ? aqA1 : aqB1;
    const bool diag = (kt == Tlim);

    short4v pk[4];
    __builtin_amdgcn_s_setprio(1);
#pragma unroll
    for (int t = 0; t < 4; ++t){
      const int krow = 16 * t + l15;
      const u16* kbase = &Kt[cur][krow * 64];
      short8 bk0 = *(const short8*)&kbase[((l4)     ^ (krow & 7)) * 8];
      short8 bk1 = *(const short8*)&kbase[((4 + l4) ^ (krow & 7)) * 8];
      f32x4 sf = {0.f, 0.f, 0.f, 0.f};
      sf = __builtin_amdgcn_mfma_f32_16x16x32_bf16(bk0, a0, sf, 0, 0, 0);
      sf = __builtin_amdgcn_mfma_f32_16x16x32_bf16(bk1, a1, sf, 0, 0, 0);
      unsigned int rw = relc[t];
      const int kk = 16 * t + 4 * l4;
#pragma unroll
      for (int r = 0; r < 4; ++r){
        float sc = sf[r] * remb[(rw >> (8 * r)) & 255];
        if (diag) sc = (kk + r <= w * 16 + l15) ? sc : 0.f;
        float p = __builtin_amdgcn_exp2f(sc);
        rsum += p;
        pk[t][r] = (short)f2bf(p);
      }
    }
    asm volatile("s_nop 2" :::);
#pragma unroll
    for (int ni = 0; ni < 4; ++ni){
      const int drow = ni * 16 + l15;
      const u16* vbase = &Vt[cur][drow * 64];
      short8 vv0 = *(const short8*)&vbase[(((2 * l4)     ^ (drow & 7))) * 8];
      short8 vv1 = *(const short8*)&vbase[(((2 * l4 + 1) ^ (drow & 7))) * 8];
      short4v va0 = {vv0[0], vv0[1], vv0[2], vv0[3]};
      short4v va1 = {vv0[4], vv0[5], vv0[6], vv0[7]};
      short4v va2 = {vv1[0], vv1[1], vv1[2], vv1[3]};
      short4v va3 = {vv1[4], vv1[5], vv1[6], vv1[7]};
      acc[ni] = mfma16(va0, pk[0], acc[ni]);
      acc[ni] = mfma16(va1, pk[1], acc[ni]);
      acc[ni] = mfma16(va2, pk[2], acc[ni]);
      acc[ni] = mfma16(va3, pk[3], acc[ni]);
    }
    __builtin_amdgcn_s_setprio(0);

    if (isA && it == TA){
      writeout(TA, q0A);
#pragma unroll
      for (int ni = 0; ni < 4; ++ni) acc[ni] = f32x4{0.f, 0.f, 0.f, 0.f};
      rsum = 0.f;
    }
#pragma unroll
    for (int t = 0; t < 4; ++t) relc[t] = reln[t];
    __syncthreads();
  }
#undef STAGE
  writeout(TB, q0B);
}

// ---------------- launch ----------------
extern "C" void kernel_launch(void* const* d_in, const int* in_sizes, int n_in,
                              void* d_out, int out_size, void* d_ws, size_t ws_size,
                              hipStream_t stream){
  const float* x       = (const float*)d_in[0];
  const float* Wqkv    = (const float*)d_in[1];
  const float* bqkv    = (const float*)d_in[2];
  const float* Wproj   = (const float*)d_in[3];
  const float* bproj   = (const float*)d_in[4];
  const float* rel_emb = (const float*)d_in[5];
  const int*   rel     = (const int*)d_in[6];
  float* out = (float*)d_out;

  char* ws = (char*)d_ws;
  u16* xb     = (u16*)(ws);                      // 8 MB (x bf16; later reused as attn output)
  u16* wqkvT  = (u16*)(ws + (8ull  << 20));      // 6 MB
  u16* wprojT = (u16*)(ws + (14ull << 20));      // 2 MB
  u16* qb     = (u16*)(ws + (16ull << 20));      // 8 MB
  u16* kb     = (u16*)(ws + (24ull << 20));      // 8 MB
  u16* vb     = (u16*)(ws + (32ull << 20));      // 8 MB
  u16* vtb    = (u16*)(ws + (40ull << 20));      // 8 MB
  float* vsuf = (float*)(ws + (48ull << 20));    // 270 KB
  float* vpart= (float*)(ws + (48ull << 20) + (512ull << 10)); // 256 KB
  u8*   rel8  = (u8*)(ws + (49ull << 20));       // 8.4 MB (only if ws allows)
  const bool useU8 = ws_size >= (58ull << 20);

  cvt_k<<<4096, 256, 0, stream>>>(x, xb, 1048576);
  tconv_k<<<dim3(96, 32), dim3(32, 8), 0, stream>>>(Wqkv, wqkvT, 1024, 3072);
  tconv_k<<<dim3(32, 32), dim3(32, 8), 0, stream>>>(Wproj, wprojT, 1024, 1024);
  if (useU8) rel8_k<<<8192, 256, 0, stream>>>(rel, rel8, 2097152);
  gemm_bt_k<0><<<dim3(24, 32), 256, 0, stream>>>(xb, wqkvT, bqkv, qb, kb, vb, nullptr, 4096, 3072, 1024);
  transpose_v_k<<<1024, 256, 0, stream>>>(vb, vtb, vpart);
  vsufscan_k<<<32, 64, 0, stream>>>(vpart, vsuf);
  if (useU8)
    attn_k<1><<<dim3(16, 32), 256, 0, stream>>>(qb, kb, vtb, vsuf, rel8, rel_emb, xb);
  else
    attn_k<0><<<dim3(16, 32), 256, 0, stream>>>(qb, kb, vtb, vsuf, rel, rel_emb, xb);
  gemm_bt_k<1><<<dim3(8, 32), 256, 0, stream>>>(xb, wprojT, bproj, nullptr, nullptr, nullptr, out, 4096, 1024, 1024);
}